// Round 18
// baseline (268.980 us; speedup 1.0000x reference)
//
#include <hip/hip_runtime.h>
#include <hip/hip_bf16.h>
#include <math.h>

// B=8, N=1024, F=64, HEADS=8, u1=128, u2=64
#define NB 8
#define NN 1024
#define NH 8

typedef __attribute__((ext_vector_type(8))) short bf16x8;
typedef __attribute__((ext_vector_type(4))) float f32x4;
typedef unsigned int u32;
typedef unsigned short u16;

__device__ __forceinline__ u16 f2bf(float f) {
    union { float f; u32 u; } v; v.f = f;
    const u32 u = v.u;
    return (u16)((u + 0x7fffu + ((u >> 16) & 1u)) >> 16);
}

// packed f32x2 -> bf16x2 (RTNE), dst.lo = lo, dst.hi = hi
__device__ __forceinline__ u32 cvt_pk_bf16(float lo, float hi) {
    u32 r;
    asm("v_cvt_pk_bf16_f32 %0, %1, %2" : "=v"(r) : "v"(lo), "v"(hi));
    return r;
}

// ---------------------------------------------------------------------------
// Mask bit-pack: A [B,N,N] f32 (0/1) -> bits [B*N, 32] u32 (bit=1 => masked)
// ---------------------------------------------------------------------------
__global__ __launch_bounds__(256) void mask_bits(const float* __restrict__ A,
                                                 u32* __restrict__ bits) {
    const int row = blockIdx.x;            // 0..B*N-1
    const int tid = threadIdx.x;
    const int lane = tid & 63;
    const float* __restrict__ ar = A + (size_t)row * NN;
#pragma unroll
    for (int it = 0; it < 4; ++it) {
        const int i = it * 256 + tid;
        const unsigned long long bal = __ballot(ar[i] != 0.0f);
        const int w0 = (it * 256 + (tid & ~63)) >> 5;
        if (lane == 0)  bits[(size_t)row * 32 + w0]     = (u32)bal;
        if (lane == 32) bits[(size_t)row * 32 + w0 + 1] = (u32)(bal >> 32);
    }
}

// ---------------------------------------------------------------------------
// f32 -> bf16 vector convert (8 elems/thread).
// ---------------------------------------------------------------------------
__global__ __launch_bounds__(256)
void cvt_bf16(const float* __restrict__ in, u16* __restrict__ out) {
    const int i = blockIdx.x * 256 + threadIdx.x;
    const float4 a = ((const float4*)in)[2 * i];
    const float4 b = ((const float4*)in)[2 * i + 1];
    u16 t[8] = {f2bf(a.x), f2bf(a.y), f2bf(a.z), f2bf(a.w),
                f2bf(b.x), f2bf(b.y), f2bf(b.z), f2bf(b.w)};
    ((uint4*)out)[i] = *(uint4*)t;
}

// ---------------------------------------------------------------------------
// QKV weight transpose+bf16: WT[c][f] over c in [0,3*HD) = {Wq|Wk|Wv}[f][c%HD]
// ---------------------------------------------------------------------------
template <int KIN, int HD>
__global__ __launch_bounds__(256)
void cvt_qkvT(const float* __restrict__ Wq, const float* __restrict__ Wk,
              const float* __restrict__ Wv, u16* __restrict__ WT) {
    const int idx = blockIdx.x * 256 + threadIdx.x;   // c*(KIN/8) + f8
    const int c  = idx / (KIN / 8);
    const int f0 = (idx % (KIN / 8)) * 8;
    const float* __restrict__ W = (c < HD) ? Wq : (c < 2 * HD) ? Wk : Wv;
    const int cc = c % HD;
    u16 tmp[8];
#pragma unroll
    for (int j = 0; j < 8; ++j)
        tmp[j] = f2bf(W[(size_t)(f0 + j) * HD + cc]);
    *(uint4*)&WT[(size_t)c * KIN + f0] = *(uint4*)tmp;
}

// ---------------------------------------------------------------------------
// Wo transpose+bf16: WoT[n][k] = bf16(Wo[k][n]).
// ---------------------------------------------------------------------------
template <int CIN, int COUT>
__global__ __launch_bounds__(256)
void cvt_woT(const float* __restrict__ Wo, u16* __restrict__ WoT) {
    const int idx = blockIdx.x * 256 + threadIdx.x;   // n*CIN/8 + k8
    const int n  = idx / (CIN / 8);
    const int k0 = (idx % (CIN / 8)) * 8;
    u16 tmp[8];
#pragma unroll
    for (int j = 0; j < 8; ++j)
        tmp[j] = f2bf(Wo[(size_t)(k0 + j) * COUT + n]);
    *(uint4*)&WoT[(size_t)n * CIN + k0] = *(uint4*)tmp;
}

// ---------------------------------------------------------------------------
// MFMA QKV projection (R12-verified).  Xb: [rows][KIN] bf16.  WT: [3*HD][KIN].
// Outputs: Qb [bh][n][D] (x qscale), Kb same, VT 32-key-group-major permuted
// [bh][grp32][D][32''] with n'' = 8g + r + 4*grp for this 16-row tile.
// ---------------------------------------------------------------------------
template <int KIN, int HD, int D>
__global__ __launch_bounds__(256)
void proj_mfma(const u16* __restrict__ Xb,
               const u16* __restrict__ WT,
               u16* __restrict__ Qb,
               u16* __restrict__ Kb,
               u16* __restrict__ VT,
               const float qscale) {
    constexpr int NKT = KIN / 32;          // k-steps (2 / 4)
    constexpr int NTW = (3 * HD / 16) / 4; // n-tiles per wave (48 / 24)

    const int tid  = threadIdx.x;
    const int w    = tid >> 6;
    const int lane = tid & 63;
    const int g    = lane >> 4;
    const int q16  = lane & 15;
    const int r0   = blockIdx.x * 16;
    const int b    = r0 >> 10;
    const int n0   = r0 & 1023;
    const int ch   = n0 >> 5;
    const int grp  = (n0 >> 4) & 1;

    bf16x8 af[NKT];
#pragma unroll
    for (int t = 0; t < NKT; ++t)
        af[t] = *(const bf16x8*)&Xb[(size_t)(r0 + q16) * KIN + t * 32 + g * 8];

#pragma unroll 1
    for (int i = 0; i < NTW; ++i) {
        const int nt = w + 4 * i;
        const int c0 = nt * 16;
        f32x4 acc = (f32x4)0.f;
#pragma unroll
        for (int t = 0; t < NKT; ++t) {
            const bf16x8 wf = *(const bf16x8*)&WT[(size_t)(c0 + q16) * KIN + t * 32 + g * 8];
            acc = __builtin_amdgcn_mfma_f32_16x16x32_bf16(af[t], wf, acc, 0, 0, 0);
        }

        const int wcl = c0 / HD;           // 0=Q 1=K 2=V (wave-uniform)
        const int cc  = c0 % HD;
        const int h   = cc / D;
        const int d0  = cc % D;
        const int bh  = b * NH + h;

        if (wcl == 2) {
            u16 tmp[4];
#pragma unroll
            for (int r = 0; r < 4; ++r) tmp[r] = f2bf(acc[r]);
            *(uint2*)&VT[(((size_t)bh * 32 + ch) * D + d0 + q16) * 32
                         + 8 * g + 4 * grp] = *(uint2*)tmp;
        } else {
            u16* __restrict__ O = wcl ? Kb : Qb;
            const float sc = wcl ? 1.0f : qscale;
#pragma unroll
            for (int r = 0; r < 4; ++r)
                O[((size_t)bh * NN + n0 + 4 * g + r) * D + d0 + q16] = f2bf(acc[r] * sc);
        }
    }
}

// ---------------------------------------------------------------------------
// MFMA flash attention v13 = v11 (R16-measured) generalized over KVBLK.
// K LDS swizzled + double-buffered; V LDS (stride 2*KVBLK+16 B) + dbuf;
// l via ones-MFMA (shuffle-free epilogue); mask-as-select; setprio on MFMA;
// one barrier per chunk; loads issued 2 chunks ahead.
// D=128 uses KVBLK=64 (exact v11 schedule, vf preloaded);
// D=64 uses KVBLK=128 (8 chunks: halves per-chunk fixed costs; vf loaded
// per-32-key-group inside PV to cap register liveness).
// Grid 512 blocks = 8 XCDs x 8 bh x 8 q-blocks; block = 4 waves x 32q.
// ---------------------------------------------------------------------------
template <int D, int KVBLK>
__global__ __launch_bounds__(256, 2)
void attn_v13(const u16* __restrict__ Qb,
              const u16* __restrict__ Kb,
              const u16* __restrict__ VT,
              const u32* __restrict__ bits,
              u16* __restrict__ Ob) {
    constexpr int ND4 = D / 32;            // QK k-steps per 16-key subtile
    constexpr int NDT = D / 16;            // PV d-tiles
    constexpr int NCH = NN / KVBLK;        // chunks (16 / 8)
    constexpr int NKB = KVBLK / 16;        // 16-key subtiles per chunk (4 / 8)
    constexpr int NKG = KVBLK / 32;        // 32-key groups per chunk (2 / 4)
    constexpr int KROWB = 2 * D;           // K LDS row bytes
    constexpr int KBYTES = KVBLK * KROWB;  // 16K
    constexpr int VROWB = 2 * KVBLK + 16;  // 144 / 272
    constexpr int VBYTES = D * VROWB;      // 18K / 17K
    constexpr int KTPR = KROWB / 64;       // threads per K row (4 / 2)
    constexpr bool VPRE = (NKG <= 2);      // preload all vf (v11 schedule)

    const int tid  = threadIdx.x;
    const int w    = tid >> 6;
    const int lane = tid & 63;
    const int g    = lane >> 4;            // 0..3
    const int q16  = lane & 15;

    // 512 blocks -> 8 XCDs x 8 bh x 8 q-blocks (bijective; bid%8 = XCD)
    const int xcd    = blockIdx.x & 7;
    const int within = blockIdx.x >> 3;    // 0..63
    const int bh     = xcd * 8 + (within >> 3);
    const int b      = bh >> 3, h = bh & 7;
    const int q0     = ((within & 7) * 4 + w) * 32;   // 32 q-rows per wave

    const u16* __restrict__ qbase = Qb + (size_t)bh * NN * D;
    const u16* __restrict__ kbase = Kb + (size_t)bh * NN * D;
    const u16* __restrict__ vbase = VT + (size_t)bh * 32 * D * 32;  // grp32-major
    const u32* __restrict__ brow0 = bits + ((size_t)b * NN + q0 + q16) * 32;
    const u32* __restrict__ brow1 = brow0 + 16 * 32;

    __shared__ alignas(16) char KsB[2][KBYTES];
    __shared__ alignas(16) char VsB[2][VBYTES];

    // staging mapping: 64B K + 64B V per thread
    const int kRow = tid / KTPR;
    const int kU0  = (tid % KTPR) * 4;
    const int vD   = tid / NKG;
    const int vSeg = tid % NKG;

    // Q as B-fragment: col=q16=q, k = f*32 + g*8 + j; 2 q-subtiles
    bf16x8 qf[2][ND4];
#pragma unroll
    for (int qs = 0; qs < 2; ++qs)
#pragma unroll
        for (int f = 0; f < ND4; ++f)
            qf[qs][f] = *(const bf16x8*)
                &qbase[(size_t)(q0 + qs * 16 + q16) * D + f * 32 + g * 8];

    f32x4 acc[2][NDT];
    f32x4 accL[2];
#pragma unroll
    for (int qs = 0; qs < 2; ++qs) {
        accL[qs] = (f32x4)0.f;
#pragma unroll
        for (int dt = 0; dt < NDT; ++dt) acc[qs][dt] = (f32x4)0.f;
    }

    const short oneb = (short)0x3F80;      // bf16 1.0
    const bf16x8 ones = {oneb, oneb, oneb, oneb, oneb, oneb, oneb, oneb};

    uint4 skr[4], svr[4];
    auto stage_load = [&](int ch) {
        const u16* ksrc = kbase + (size_t)(ch * KVBLK + kRow) * D + kU0 * 8;
#pragma unroll
        for (int i = 0; i < 4; ++i) skr[i] = *(const uint4*)(ksrc + i * 8);
        const u16* vsrc = vbase + ((size_t)(ch * NKG + vSeg) * D + vD) * 32;
#pragma unroll
        for (int i = 0; i < 4; ++i) svr[i] = *(const uint4*)(vsrc + i * 8);
    };
    auto stage_write = [&](int buf) {
        char* kr = KsB[buf] + kRow * KROWB;
#pragma unroll
        for (int i = 0; i < 4; ++i)
            *(uint4*)(kr + (((kU0 + i) ^ (kRow & 7)) * 16)) = skr[i];
        char* vr = VsB[buf] + vD * VROWB + vSeg * 64;
#pragma unroll
        for (int i = 0; i < 4; ++i) *(uint4*)(vr + i * 16) = svr[i];
    };

    // prologue: buf0 = chunk 0; chunk 1 in regs
    stage_load(0);
    stage_write(0);
    stage_load(1);
    __syncthreads();

#pragma unroll 1
    for (int ch = 0; ch < NCH; ++ch) {
        const int cur = ch & 1;
        if (ch + 1 < NCH) stage_write(cur ^ 1);
        if (ch + 2 < NCH) stage_load(ch + 2);

        u32 bw0[NKG], bw1[NKG];
#pragma unroll
        for (int i = 0; i < NKG; ++i) {
            bw0[i] = brow0[ch * NKG + i];
            bw1[i] = brow1[ch * NKG + i];
        }

        // QK^T over NKB 16-key subtiles (kf loaded per-subtile)
        f32x4 s[2][NKB];
#pragma unroll
        for (int qs = 0; qs < 2; ++qs)
#pragma unroll
            for (int kb = 0; kb < NKB; ++kb) s[qs][kb] = (f32x4)0.f;

        __builtin_amdgcn_s_setprio(1);
#pragma unroll
        for (int kb = 0; kb < NKB; ++kb) {
            bf16x8 kf[ND4];
#pragma unroll
            for (int f = 0; f < ND4; ++f)
                kf[f] = *(const bf16x8*)
                    (KsB[cur] + (kb * 16 + q16) * KROWB + (((f * 4 + g) ^ (q16 & 7)) * 16));
#pragma unroll
            for (int f = 0; f < ND4; ++f) {
                s[0][kb] = __builtin_amdgcn_mfma_f32_16x16x32_bf16(kf[f], qf[0][f], s[0][kb], 0, 0, 0);
                s[1][kb] = __builtin_amdgcn_mfma_f32_16x16x32_bf16(kf[f], qf[1][f], s[1][kb], 0, 0, 0);
            }
        }
        __builtin_amdgcn_s_setprio(0);

        // vf preload (v11 schedule) only for small NKG
        bf16x8 vfp[VPRE ? 2 : 1][NDT];
        if constexpr (VPRE) {
#pragma unroll
            for (int kg = 0; kg < 2; ++kg)
#pragma unroll
                for (int dt = 0; dt < NDT; ++dt)
                    vfp[kg][dt] = *(const bf16x8*)
                        (VsB[cur] + (dt * 16 + q16) * VROWB + kg * 64 + g * 16);
        }

        // softmax (no max tracking): reg r of s[qs][kb] = key kb*16+4g+r
        union { u32 u[4]; bf16x8 v; } pa[2][NKG];
#pragma unroll
        for (int qs = 0; qs < 2; ++qs) {
#pragma unroll
            for (int kb = 0; kb < NKB; ++kb) {
                const u32 bwv = qs ? bw1[kb >> 1] : bw0[kb >> 1];
                const u32 sh = bwv >> (g * 4 + (kb & 1) * 16);
                float p[4];
#pragma unroll
                for (int r = 0; r < 4; ++r) {
                    const float e = exp2f(s[qs][kb][r]);
                    p[r] = ((sh >> r) & 1u) ? 0.f : e;
                }
                pa[qs][kb >> 1].u[(kb & 1) * 2 + 0] = cvt_pk_bf16(p[0], p[1]);
                pa[qs][kb >> 1].u[(kb & 1) * 2 + 1] = cvt_pk_bf16(p[2], p[3]);
            }
        }

        // PV + l-via-ones MFMA
        __builtin_amdgcn_s_setprio(1);
#pragma unroll
        for (int kg = 0; kg < NKG; ++kg) {
            accL[0] = __builtin_amdgcn_mfma_f32_16x16x32_bf16(pa[0][kg].v, ones, accL[0], 0, 0, 0);
            accL[1] = __builtin_amdgcn_mfma_f32_16x16x32_bf16(pa[1][kg].v, ones, accL[1], 0, 0, 0);
#pragma unroll
            for (int dt = 0; dt < NDT; ++dt) {
                bf16x8 vf;
                if constexpr (VPRE) vf = vfp[kg][dt];
                else vf = *(const bf16x8*)
                    (VsB[cur] + (dt * 16 + q16) * VROWB + kg * 64 + g * 16);
                acc[0][dt] = __builtin_amdgcn_mfma_f32_16x16x32_bf16(pa[0][kg].v, vf, acc[0][dt], 0, 0, 0);
                acc[1][dt] = __builtin_amdgcn_mfma_f32_16x16x32_bf16(pa[1][kg].v, vf, acc[1][dt], 0, 0, 0);
            }
        }
        __builtin_amdgcn_s_setprio(0);

        __syncthreads();
    }

    // epilogue: accL[qs][r] = l for q-row g*4+r (C-layout) -> no shuffles
#pragma unroll
    for (int qs = 0; qs < 2; ++qs) {
        float ivr[4];
#pragma unroll
        for (int r = 0; r < 4; ++r) ivr[r] = 1.0f / accL[qs][r];
#pragma unroll
        for (int dt = 0; dt < NDT; ++dt)
#pragma unroll
            for (int r = 0; r < 4; ++r) {
                const int q = q0 + qs * 16 + g * 4 + r;
                Ob[(((size_t)b * NN + q) * NH + h) * D + dt * 16 + q16] =
                    f2bf(acc[qs][dt][r] * ivr[r]);
            }
    }
}

// ---------------------------------------------------------------------------
// Output projection via MFMA (R11/R12-verified).
// ---------------------------------------------------------------------------
template <int CIN, int COUT, bool BF16OUT>
__global__ __launch_bounds__(256)
void wo_mfma(const u16* __restrict__ ctxb,
             const u16* __restrict__ WoT,
             void* __restrict__ Hout) {
    constexpr int NTW = COUT / 64;         // n-tiles per wave (2 / 1)
    const int tid  = threadIdx.x;
    const int w    = tid >> 6;
    const int lane = tid & 63;
    const int g    = lane >> 4;
    const int q16  = lane & 15;
    const int r0   = blockIdx.x * 16;

    f32x4 acc[NTW];
#pragma unroll
    for (int nt = 0; nt < NTW; ++nt) acc[nt] = (f32x4)0.f;

    const u16* __restrict__ arow = ctxb + (size_t)(r0 + q16) * CIN + g * 8;

#pragma unroll 4
    for (int k0 = 0; k0 < CIN; k0 += 32) {
        const bf16x8 af = *(const bf16x8*)(arow + k0);
#pragma unroll
        for (int nt = 0; nt < NTW; ++nt) {
            const int n = (w * NTW + nt) * 16 + q16;
            const bf16x8 wf = *(const bf16x8*)&WoT[(size_t)n * CIN + k0 + g * 8];
            acc[nt] = __builtin_amdgcn_mfma_f32_16x16x32_bf16(af, wf, acc[nt], 0, 0, 0);
        }
    }

#pragma unroll
    for (int nt = 0; nt < NTW; ++nt)
#pragma unroll
        for (int r = 0; r < 4; ++r) {
            const size_t off = (size_t)(r0 + 4 * g + r) * COUT + (w * NTW + nt) * 16 + q16;
            if constexpr (BF16OUT) ((u16*)Hout)[off] = f2bf(acc[nt][r]);
            else                   ((float*)Hout)[off] = acc[nt][r];
        }
}

// ---------------------------------------------------------------------------
// Pool stage 1: partial sums.  Grid 256 blocks = 8 b x 32 chunks of 32 rows.
// ---------------------------------------------------------------------------
__global__ __launch_bounds__(256)
void pool_partial(const float* __restrict__ H2, float* __restrict__ partial) {
    const int b  = blockIdx.x >> 5;
    const int ch = blockIdx.x & 31;
    const int tid = threadIdx.x;
    const int o = tid & 63;
    const int g = tid >> 6;

    __shared__ float red[4][64];
    float acc = 0.f;
#pragma unroll
    for (int i = 0; i < 8; ++i) {
        const int n = ch * 32 + g * 8 + i;
        acc += H2[((size_t)b * NN + n) * 64 + o];
    }
    red[g][o] = acc;
    __syncthreads();
    if (g == 0)
        partial[((size_t)b * 32 + ch) * 64 + o] =
            (red[0][o] + red[1][o]) + (red[2][o] + red[3][o]);
}

// ---------------------------------------------------------------------------
// Pool stage 2: final reduce + 3-layer MLP.  8 blocks (one per b).
// ---------------------------------------------------------------------------
__global__ __launch_bounds__(256)
void pool_mlp2(const float* __restrict__ partial,
               const float* __restrict__ W1, const float* __restrict__ b1,
               const float* __restrict__ W2, const float* __restrict__ b2,
               const float* __restrict__ W3, const float* __restrict__ b3,
               float* __restrict__ out) {
    const int b = blockIdx.x;
    const int tid = threadIdx.x;       // 256
    const int o = tid & 63;
    const int g = tid >> 6;
    __shared__ float red[4][64];
    __shared__ float mean[64];
    __shared__ float h1[32];
    __shared__ float h2[16];

    float acc = 0.f;
#pragma unroll
    for (int c = 0; c < 8; ++c)
        acc += partial[((size_t)b * 32 + g * 8 + c) * 64 + o];
    red[g][o] = acc;
    __syncthreads();
    if (g == 0)
        mean[o] = ((red[0][o] + red[1][o]) + (red[2][o] + red[3][o])) * (1.0f / 1024.0f);
    __syncthreads();

    if (tid < 32) {
        float a = b1[tid];
#pragma unroll
        for (int f = 0; f < 64; ++f) a = fmaf(mean[f], W1[f * 32 + tid], a);
        h1[tid] = fmaxf(a, 0.f);
    }
    __syncthreads();
    if (tid < 16) {
        float a = b2[tid];
#pragma unroll
        for (int f = 0; f < 32; ++f) a = fmaf(h1[f], W2[f * 16 + tid], a);
        h2[tid] = fmaxf(a, 0.f);
    }
    __syncthreads();
    if (tid == 0) {
        float a = b3[0];
#pragma unroll
        for (int f = 0; f < 16; ++f) a = fmaf(h2[f], W3[f], a);
        out[b] = a;
    }
}

// ---------------------------------------------------------------------------
extern "C" void kernel_launch(void* const* d_in, const int* in_sizes, int n_in,
                              void* d_out, int out_size, void* d_ws, size_t ws_size,
                              hipStream_t stream) {
    const float* X   = (const float*)d_in[0];
    const float* A   = (const float*)d_in[1];
    const float* Wq1 = (const float*)d_in[2];
    const float* Wk1 = (const float*)d_in[3];
    const float* Wv1 = (const float*)d_in[4];
    const float* Wo1 = (const float*)d_in[5];
    const float* Wq2 = (const float*)d_in[6];
    const float* Wk2 = (const float*)d_in[7];
    const float* Wv2 = (const float*)d_in[8];
    const float* Wo2 = (const float*)d_in[9];
    const float* W1  = (const float*)d_in[10];
    const float* b1  = (const float*)d_in[11];
    const float* W2  = (const float*)d_in[12];
    const float* b2  = (const float*)d_in[13];
    const float* W3  = (const float*)d_in[14];
    const float* b3  = (const float*)d_in[15];
    float* out = (float*)d_out;

    // workspace layout (u16 units unless noted)
    u32* bits   = (u32*)d_ws;                      // 1 MB
    u16* base   = (u16*)(bits + 262144);
    u16* Qb1    = base;  base += 8388608;
    u16* Kb1    = base;  base += 8388608;
    u16* VT1    = base;  base += 8388608;          // 32-key-group-major V
    u16* ctx1b  = base;  base += 8388608;          // bf16 ctx [B,N,1024]
    u16* WoT1   = base;  base += 131072;           // [128][1024]
    u16* Qb2    = base;  base += 4194304;
    u16* Kb2    = base;  base += 4194304;
    u16* VT2    = base;  base += 4194304;
    u16* ctx2b  = base;  base += 4194304;          // bf16 ctx [B,N,512]
    u16* WoT2   = base;  base += 32768;            // [64][512]
    u16* Xb     = base;  base += 524288;           // bf16 X [8192][64]
    u16* WqkvT1 = base;  base += 196608;           // [3072][64]
    u16* WqkvT2 = base;  base += 196608;           // [1536][128]
    u16* H1b    = base;  base += 1048576;          // bf16 H1 [8192][128]
    float* H2   = (float*)base;                    // f32 [B,N,64] (1MB floats)
    float* partial = H2 + 524288;                  // f32 [8][32][64]

    const int ROWS = NB * NN;                     // 8192
    const float LOG2E = 1.4426950408889634f;

    // prep (independent)
    mask_bits<<<ROWS, 256, 0, stream>>>(A, bits);
    cvt_bf16<<<ROWS * 64 / 8 / 256, 256, 0, stream>>>(X, Xb);
    cvt_qkvT<64, 1024><<<3072 * 64 / 8 / 256, 256, 0, stream>>>(Wq1, Wk1, Wv1, WqkvT1);
    cvt_qkvT<128, 512><<<1536 * 128 / 8 / 256, 256, 0, stream>>>(Wq2, Wk2, Wv2, WqkvT2);
    cvt_woT<1024, 128><<<128 * 1024 / 8 / 256, 256, 0, stream>>>(Wo1, WoT1);
    cvt_woT<512, 64><<<64 * 512 / 8 / 256, 256, 0, stream>>>(Wo2, WoT2);

    // ----- layer 1 (D = 128) -----
    proj_mfma<64, 1024, 128><<<ROWS / 16, 256, 0, stream>>>(
        Xb, WqkvT1, Qb1, Kb1, VT1, 0.08838834764831845f * LOG2E);
    attn_v13<128, 64><<<512, 256, 0, stream>>>(Qb1, Kb1, VT1, bits, ctx1b);
    wo_mfma<1024, 128, true><<<ROWS / 16, 256, 0, stream>>>(ctx1b, WoT1, H1b);

    // ----- layer 2 (D = 64) -----
    proj_mfma<128, 512, 64><<<ROWS / 16, 256, 0, stream>>>(
        H1b, WqkvT2, Qb2, Kb2, VT2, 0.125f * LOG2E);
    attn_v13<64, 128><<<512, 256, 0, stream>>>(Qb2, Kb2, VT2, bits, ctx2b);
    wo_mfma<512, 64, false><<<ROWS / 16, 256, 0, stream>>>(ctx2b, WoT2, H2);

    // ----- pool + MLP (2-stage: parallel reduce, tiny MLP) -----
    pool_partial<<<256, 256, 0, stream>>>(H2, partial);
    pool_mlp2<<<NB, 256, 0, stream>>>(partial, W1, b1, W2, b2, W3, b3, out);
}

// Round 19
// 218.268 us; speedup vs baseline: 1.2323x; 1.2323x over previous
//
#include <hip/hip_runtime.h>
#include <hip/hip_bf16.h>
#include <math.h>

// B=8, N=1024, F=64, HEADS=8, u1=128, u2=64
#define NB 8
#define NN 1024
#define NH 8

typedef __attribute__((ext_vector_type(8))) short bf16x8;
typedef __attribute__((ext_vector_type(4))) float f32x4;
typedef unsigned int u32;
typedef unsigned short u16;

__device__ __forceinline__ u16 f2bf(float f) {
    union { float f; u32 u; } v; v.f = f;
    const u32 u = v.u;
    return (u16)((u + 0x7fffu + ((u >> 16) & 1u)) >> 16);
}

// packed f32x2 -> bf16x2 (RTNE), dst.lo = lo, dst.hi = hi
__device__ __forceinline__ u32 cvt_pk_bf16(float lo, float hi) {
    u32 r;
    asm("v_cvt_pk_bf16_f32 %0, %1, %2" : "=v"(r) : "v"(lo), "v"(hi));
    return r;
}

// ---------------------------------------------------------------------------
// Mask bit-pack: A [B,N,N] f32 (0/1) -> bits [B*N, 32] u32 (bit=1 => masked)
// ---------------------------------------------------------------------------
__global__ __launch_bounds__(256) void mask_bits(const float* __restrict__ A,
                                                 u32* __restrict__ bits) {
    const int row = blockIdx.x;            // 0..B*N-1
    const int tid = threadIdx.x;
    const int lane = tid & 63;
    const float* __restrict__ ar = A + (size_t)row * NN;
#pragma unroll
    for (int it = 0; it < 4; ++it) {
        const int i = it * 256 + tid;
        const unsigned long long bal = __ballot(ar[i] != 0.0f);
        const int w0 = (it * 256 + (tid & ~63)) >> 5;
        if (lane == 0)  bits[(size_t)row * 32 + w0]     = (u32)bal;
        if (lane == 32) bits[(size_t)row * 32 + w0 + 1] = (u32)(bal >> 32);
    }
}

// ---------------------------------------------------------------------------
// f32 -> bf16 vector convert (8 elems/thread).
// ---------------------------------------------------------------------------
__global__ __launch_bounds__(256)
void cvt_bf16(const float* __restrict__ in, u16* __restrict__ out) {
    const int i = blockIdx.x * 256 + threadIdx.x;
    const float4 a = ((const float4*)in)[2 * i];
    const float4 b = ((const float4*)in)[2 * i + 1];
    u16 t[8] = {f2bf(a.x), f2bf(a.y), f2bf(a.z), f2bf(a.w),
                f2bf(b.x), f2bf(b.y), f2bf(b.z), f2bf(b.w)};
    ((uint4*)out)[i] = *(uint4*)t;
}

// ---------------------------------------------------------------------------
// QKV weight transpose+bf16: WT[c][f] over c in [0,3*HD) = {Wq|Wk|Wv}[f][c%HD]
// ---------------------------------------------------------------------------
template <int KIN, int HD>
__global__ __launch_bounds__(256)
void cvt_qkvT(const float* __restrict__ Wq, const float* __restrict__ Wk,
              const float* __restrict__ Wv, u16* __restrict__ WT) {
    const int idx = blockIdx.x * 256 + threadIdx.x;   // c*(KIN/8) + f8
    const int c  = idx / (KIN / 8);
    const int f0 = (idx % (KIN / 8)) * 8;
    const float* __restrict__ W = (c < HD) ? Wq : (c < 2 * HD) ? Wk : Wv;
    const int cc = c % HD;
    u16 tmp[8];
#pragma unroll
    for (int j = 0; j < 8; ++j)
        tmp[j] = f2bf(W[(size_t)(f0 + j) * HD + cc]);
    *(uint4*)&WT[(size_t)c * KIN + f0] = *(uint4*)tmp;
}

// ---------------------------------------------------------------------------
// Wo transpose+bf16: WoT[n][k] = bf16(Wo[k][n]).
// ---------------------------------------------------------------------------
template <int CIN, int COUT>
__global__ __launch_bounds__(256)
void cvt_woT(const float* __restrict__ Wo, u16* __restrict__ WoT) {
    const int idx = blockIdx.x * 256 + threadIdx.x;   // n*CIN/8 + k8
    const int n  = idx / (CIN / 8);
    const int k0 = (idx % (CIN / 8)) * 8;
    u16 tmp[8];
#pragma unroll
    for (int j = 0; j < 8; ++j)
        tmp[j] = f2bf(Wo[(size_t)(k0 + j) * COUT + n]);
    *(uint4*)&WoT[(size_t)n * CIN + k0] = *(uint4*)tmp;
}

// ---------------------------------------------------------------------------
// MFMA QKV projection (R12-verified).  Xb: [rows][KIN] bf16.  WT: [3*HD][KIN].
// Outputs: Qb [bh][n][D] (x qscale), Kb same, VT 32-key-group-major permuted
// [bh][grp32][D][32''] with n'' = 8g + r + 4*grp for this 16-row tile.
// ---------------------------------------------------------------------------
template <int KIN, int HD, int D>
__global__ __launch_bounds__(256)
void proj_mfma(const u16* __restrict__ Xb,
               const u16* __restrict__ WT,
               u16* __restrict__ Qb,
               u16* __restrict__ Kb,
               u16* __restrict__ VT,
               const float qscale) {
    constexpr int NKT = KIN / 32;          // k-steps (2 / 4)
    constexpr int NTW = (3 * HD / 16) / 4; // n-tiles per wave (48 / 24)

    const int tid  = threadIdx.x;
    const int w    = tid >> 6;
    const int lane = tid & 63;
    const int g    = lane >> 4;
    const int q16  = lane & 15;
    const int r0   = blockIdx.x * 16;
    const int b    = r0 >> 10;
    const int n0   = r0 & 1023;
    const int ch   = n0 >> 5;
    const int grp  = (n0 >> 4) & 1;

    bf16x8 af[NKT];
#pragma unroll
    for (int t = 0; t < NKT; ++t)
        af[t] = *(const bf16x8*)&Xb[(size_t)(r0 + q16) * KIN + t * 32 + g * 8];

#pragma unroll 1
    for (int i = 0; i < NTW; ++i) {
        const int nt = w + 4 * i;
        const int c0 = nt * 16;
        f32x4 acc = (f32x4)0.f;
#pragma unroll
        for (int t = 0; t < NKT; ++t) {
            const bf16x8 wf = *(const bf16x8*)&WT[(size_t)(c0 + q16) * KIN + t * 32 + g * 8];
            acc = __builtin_amdgcn_mfma_f32_16x16x32_bf16(af[t], wf, acc, 0, 0, 0);
        }

        const int wcl = c0 / HD;           // 0=Q 1=K 2=V (wave-uniform)
        const int cc  = c0 % HD;
        const int h   = cc / D;
        const int d0  = cc % D;
        const int bh  = b * NH + h;

        if (wcl == 2) {
            u16 tmp[4];
#pragma unroll
            for (int r = 0; r < 4; ++r) tmp[r] = f2bf(acc[r]);
            *(uint2*)&VT[(((size_t)bh * 32 + ch) * D + d0 + q16) * 32
                         + 8 * g + 4 * grp] = *(uint2*)tmp;
        } else {
            u16* __restrict__ O = wcl ? Kb : Qb;
            const float sc = wcl ? 1.0f : qscale;
#pragma unroll
            for (int r = 0; r < 4; ++r)
                O[((size_t)bh * NN + n0 + 4 * g + r) * D + d0 + q16] = f2bf(acc[r] * sc);
        }
    }
}

// ---------------------------------------------------------------------------
// MFMA flash attention v11b = R15's attn_v11 (measured best) with ONE change:
// V LDS half-slot XOR swizzle (write slot = vHalf ^ ((vD>>3)&1), read slot =
// kg ^ ((q16>>3)&1); row = dt*16+q16 so (row>>3)&1 = (q16>>3)&1) -- makes V
// reads conflict-free and V writes 2-way (free), targeting the measured
// 5.2M SQ_LDS_BANK_CONFLICT.  Everything else byte-identical to R15.
// ---------------------------------------------------------------------------
template <int D>
__global__ __launch_bounds__(256, 2)
void attn_v11(const u16* __restrict__ Qb,
              const u16* __restrict__ Kb,
              const u16* __restrict__ VT,
              const u32* __restrict__ bits,
              u16* __restrict__ Ob) {
    constexpr int ND4 = D / 32;            // QK k-steps per 16-key subtile (4/2)
    constexpr int NDT = D / 16;            // PV d-tiles (8/4)
    constexpr int KROWB = 2 * D;           // K LDS row bytes (256/128)
    constexpr int KBYTES = 64 * KROWB;     // 16K / 8K
    constexpr int VROWB = 144;             // 64 keys * 2B + 16B pad
    constexpr int VBYTES = D * VROWB;      // 18K / 9K

    const int tid  = threadIdx.x;
    const int w    = tid >> 6;
    const int lane = tid & 63;
    const int g    = lane >> 4;            // 0..3
    const int q16  = lane & 15;

    // 512 blocks -> 8 XCDs x 8 bh x 8 q-blocks (bijective; bid%8 = XCD)
    const int xcd    = blockIdx.x & 7;
    const int within = blockIdx.x >> 3;    // 0..63
    const int bh     = xcd * 8 + (within >> 3);
    const int b      = bh >> 3, h = bh & 7;
    const int q0     = ((within & 7) * 4 + w) * 32;   // 32 q-rows per wave

    const u16* __restrict__ qbase = Qb + (size_t)bh * NN * D;
    const u16* __restrict__ kbase = Kb + (size_t)bh * NN * D;
    const u16* __restrict__ vbase = VT + (size_t)bh * 32 * D * 32;  // grp32-major
    const u32* __restrict__ brow0 = bits + ((size_t)b * NN + q0 + q16) * 32;
    const u32* __restrict__ brow1 = brow0 + 16 * 32;

    __shared__ alignas(16) char KsB[2][KBYTES];
    __shared__ alignas(16) char VsB[2][VBYTES];

    // staging mapping (64B per thread each for K and V)
    bool doK, doV;
    int kRow = 0, kU0 = 0, vD = 0, vHalf = 0;
    if constexpr (D == 128) {
        doK = true; doV = true;
        kRow = tid >> 2;           kU0 = (tid & 3) * 4;    // 64 rows x 16 units
        vD   = tid >> 1;           vHalf = tid & 1;        // 128 rows x 2 halves
    } else {
        doK = (tid < 128); doV = !doK;
        kRow = (tid & 127) >> 1;   kU0 = (tid & 1) * 4;    // 64 rows x 8 units
        vD   = (tid & 127) >> 1;   vHalf = tid & 1;        // 64 rows x 2 halves
    }
    const int vSlot = vHalf ^ ((vD >> 3) & 1);   // V write half-slot (swizzled)
    const int vxr   = (q16 >> 3) & 1;            // V read slot XOR bit

    // Q as B-fragment: col=q16=q, k = f*32 + g*8 + j; 2 q-subtiles
    bf16x8 qf[2][ND4];
#pragma unroll
    for (int qs = 0; qs < 2; ++qs)
#pragma unroll
        for (int f = 0; f < ND4; ++f)
            qf[qs][f] = *(const bf16x8*)
                &qbase[(size_t)(q0 + qs * 16 + q16) * D + f * 32 + g * 8];

    f32x4 acc[2][NDT];
    f32x4 accL[2];
#pragma unroll
    for (int qs = 0; qs < 2; ++qs) {
        accL[qs] = (f32x4)0.f;
#pragma unroll
        for (int dt = 0; dt < NDT; ++dt) acc[qs][dt] = (f32x4)0.f;
    }

    const short oneb = (short)0x3F80;      // bf16 1.0
    const bf16x8 ones = {oneb, oneb, oneb, oneb, oneb, oneb, oneb, oneb};

    uint4 skr0, skr1, skr2, skr3, svr0, svr1, svr2, svr3;
    auto stage_load = [&](int ch) {
        if (doK) {
            const u16* src = kbase + (size_t)(ch * 64 + kRow) * D + kU0 * 8;
            skr0 = *(const uint4*)(src);
            skr1 = *(const uint4*)(src + 8);
            skr2 = *(const uint4*)(src + 16);
            skr3 = *(const uint4*)(src + 24);
        }
        if (doV) {
            const u16* src = vbase + ((size_t)(ch * 2 + vHalf) * D + vD) * 32;
            svr0 = *(const uint4*)(src);
            svr1 = *(const uint4*)(src + 8);
            svr2 = *(const uint4*)(src + 16);
            svr3 = *(const uint4*)(src + 24);
        }
    };
    auto stage_write = [&](int buf) {
        if (doK) {
            char* kr = KsB[buf] + kRow * KROWB;
            *(uint4*)(kr + (((kU0 + 0) ^ (kRow & 7)) * 16)) = skr0;
            *(uint4*)(kr + (((kU0 + 1) ^ (kRow & 7)) * 16)) = skr1;
            *(uint4*)(kr + (((kU0 + 2) ^ (kRow & 7)) * 16)) = skr2;
            *(uint4*)(kr + (((kU0 + 3) ^ (kRow & 7)) * 16)) = skr3;
        }
        if (doV) {
            char* vr = VsB[buf] + vD * VROWB + vSlot * 64;
            *(uint4*)(vr)      = svr0;
            *(uint4*)(vr + 16) = svr1;
            *(uint4*)(vr + 32) = svr2;
            *(uint4*)(vr + 48) = svr3;
        }
    };

    // prologue: buf0 = chunk 0; chunk 1 in regs
    stage_load(0);
    stage_write(0);
    stage_load(1);
    __syncthreads();

#pragma unroll 1
    for (int ch = 0; ch < 16; ++ch) {
        const int cur = ch & 1;
        if (ch + 1 < 16) stage_write(cur ^ 1);
        if (ch + 2 < 16) stage_load(ch + 2);

        const uint2 bwA = *(const uint2*)(brow0 + ch * 2);
        const uint2 bwB = *(const uint2*)(brow1 + ch * 2);

        // QK^T over 4 16-key subtiles (kf loaded per-subtile to cap liveness)
        f32x4 s[2][4];
#pragma unroll
        for (int qs = 0; qs < 2; ++qs)
#pragma unroll
            for (int kb = 0; kb < 4; ++kb) s[qs][kb] = (f32x4)0.f;

        __builtin_amdgcn_s_setprio(1);
#pragma unroll
        for (int kb = 0; kb < 4; ++kb) {
            bf16x8 kf[ND4];
#pragma unroll
            for (int f = 0; f < ND4; ++f)
                kf[f] = *(const bf16x8*)
                    (KsB[cur] + (kb * 16 + q16) * KROWB + (((f * 4 + g) ^ (q16 & 7)) * 16));
#pragma unroll
            for (int f = 0; f < ND4; ++f) {
                s[0][kb] = __builtin_amdgcn_mfma_f32_16x16x32_bf16(kf[f], qf[0][f], s[0][kb], 0, 0, 0);
                s[1][kb] = __builtin_amdgcn_mfma_f32_16x16x32_bf16(kf[f], qf[1][f], s[1][kb], 0, 0, 0);
            }
        }
        __builtin_amdgcn_s_setprio(0);

        // V B-fragments (issue LDS reads before softmax for overlap);
        // read slot = kg ^ vxr matches the write-side swizzle
        bf16x8 vf[2][NDT];
#pragma unroll
        for (int kg = 0; kg < 2; ++kg)
#pragma unroll
            for (int dt = 0; dt < NDT; ++dt)
                vf[kg][dt] = *(const bf16x8*)
                    (VsB[cur] + (dt * 16 + q16) * VROWB + (kg ^ vxr) * 64 + g * 16);

        // softmax (no max tracking): reg r of s[qs][kb] = key kb*16+4g+r
        union { u32 u[4]; bf16x8 v; } pa[2][2];
#pragma unroll
        for (int qs = 0; qs < 2; ++qs) {
            const u32 w0 = qs ? bwB.x : bwA.x;
            const u32 w1 = qs ? bwB.y : bwA.y;
#pragma unroll
            for (int kb = 0; kb < 4; ++kb) {
                const u32 sh = ((kb >> 1) ? w1 : w0) >> (g * 4 + (kb & 1) * 16);
                float p[4];
#pragma unroll
                for (int r = 0; r < 4; ++r) {
                    const float e = exp2f(s[qs][kb][r]);
                    p[r] = ((sh >> r) & 1u) ? 0.f : e;
                }
                pa[qs][kb >> 1].u[(kb & 1) * 2 + 0] = cvt_pk_bf16(p[0], p[1]);
                pa[qs][kb >> 1].u[(kb & 1) * 2 + 1] = cvt_pk_bf16(p[2], p[3]);
            }
        }

        // PV + l-via-ones MFMA
        __builtin_amdgcn_s_setprio(1);
#pragma unroll
        for (int kg = 0; kg < 2; ++kg) {
            accL[0] = __builtin_amdgcn_mfma_f32_16x16x32_bf16(pa[0][kg].v, ones, accL[0], 0, 0, 0);
            accL[1] = __builtin_amdgcn_mfma_f32_16x16x32_bf16(pa[1][kg].v, ones, accL[1], 0, 0, 0);
#pragma unroll
            for (int dt = 0; dt < NDT; ++dt) {
                acc[0][dt] = __builtin_amdgcn_mfma_f32_16x16x32_bf16(pa[0][kg].v, vf[kg][dt], acc[0][dt], 0, 0, 0);
                acc[1][dt] = __builtin_amdgcn_mfma_f32_16x16x32_bf16(pa[1][kg].v, vf[kg][dt], acc[1][dt], 0, 0, 0);
            }
        }
        __builtin_amdgcn_s_setprio(0);

        __syncthreads();
    }

    // epilogue: accL[qs][r] = l for q-row g*4+r (C-layout) -> no shuffles
#pragma unroll
    for (int qs = 0; qs < 2; ++qs) {
        float ivr[4];
#pragma unroll
        for (int r = 0; r < 4; ++r) ivr[r] = 1.0f / accL[qs][r];
#pragma unroll
        for (int dt = 0; dt < NDT; ++dt)
#pragma unroll
            for (int r = 0; r < 4; ++r) {
                const int q = q0 + qs * 16 + g * 4 + r;
                Ob[(((size_t)b * NN + q) * NH + h) * D + dt * 16 + q16] =
                    f2bf(acc[qs][dt][r] * ivr[r]);
            }
    }
}

// ---------------------------------------------------------------------------
// Output projection via MFMA (R11/R12-verified).
// ---------------------------------------------------------------------------
template <int CIN, int COUT, bool BF16OUT>
__global__ __launch_bounds__(256)
void wo_mfma(const u16* __restrict__ ctxb,
             const u16* __restrict__ WoT,
             void* __restrict__ Hout) {
    constexpr int NTW = COUT / 64;         // n-tiles per wave (2 / 1)
    const int tid  = threadIdx.x;
    const int w    = tid >> 6;
    const int lane = tid & 63;
    const int g    = lane >> 4;
    const int q16  = lane & 15;
    const int r0   = blockIdx.x * 16;

    f32x4 acc[NTW];
#pragma unroll
    for (int nt = 0; nt < NTW; ++nt) acc[nt] = (f32x4)0.f;

    const u16* __restrict__ arow = ctxb + (size_t)(r0 + q16) * CIN + g * 8;

#pragma unroll 4
    for (int k0 = 0; k0 < CIN; k0 += 32) {
        const bf16x8 af = *(const bf16x8*)(arow + k0);
#pragma unroll
        for (int nt = 0; nt < NTW; ++nt) {
            const int n = (w * NTW + nt) * 16 + q16;
            const bf16x8 wf = *(const bf16x8*)&WoT[(size_t)n * CIN + k0 + g * 8];
            acc[nt] = __builtin_amdgcn_mfma_f32_16x16x32_bf16(af, wf, acc[nt], 0, 0, 0);
        }
    }

#pragma unroll
    for (int nt = 0; nt < NTW; ++nt)
#pragma unroll
        for (int r = 0; r < 4; ++r) {
            const size_t off = (size_t)(r0 + 4 * g + r) * COUT + (w * NTW + nt) * 16 + q16;
            if constexpr (BF16OUT) ((u16*)Hout)[off] = f2bf(acc[nt][r]);
            else                   ((float*)Hout)[off] = acc[nt][r];
        }
}

// ---------------------------------------------------------------------------
// Pool stage 1: partial sums.  Grid 256 blocks = 8 b x 32 chunks of 32 rows.
// ---------------------------------------------------------------------------
__global__ __launch_bounds__(256)
void pool_partial(const float* __restrict__ H2, float* __restrict__ partial) {
    const int b  = blockIdx.x >> 5;
    const int ch = blockIdx.x & 31;
    const int tid = threadIdx.x;
    const int o = tid & 63;
    const int g = tid >> 6;

    __shared__ float red[4][64];
    float acc = 0.f;
#pragma unroll
    for (int i = 0; i < 8; ++i) {
        const int n = ch * 32 + g * 8 + i;
        acc += H2[((size_t)b * NN + n) * 64 + o];
    }
    red[g][o] = acc;
    __syncthreads();
    if (g == 0)
        partial[((size_t)b * 32 + ch) * 64 + o] =
            (red[0][o] + red[1][o]) + (red[2][o] + red[3][o]);
}

// ---------------------------------------------------------------------------
// Pool stage 2: final reduce + 3-layer MLP.  8 blocks (one per b).
// ---------------------------------------------------------------------------
__global__ __launch_bounds__(256)
void pool_mlp2(const float* __restrict__ partial,
               const float* __restrict__ W1, const float* __restrict__ b1,
               const float* __restrict__ W2, const float* __restrict__ b2,
               const float* __restrict__ W3, const float* __restrict__ b3,
               float* __restrict__ out) {
    const int b = blockIdx.x;
    const int tid = threadIdx.x;       // 256
    const int o = tid & 63;
    const int g = tid >> 6;
    __shared__ float red[4][64];
    __shared__ float mean[64];
    __shared__ float h1[32];
    __shared__ float h2[16];

    float acc = 0.f;
#pragma unroll
    for (int c = 0; c < 8; ++c)
        acc += partial[((size_t)b * 32 + g * 8 + c) * 64 + o];
    red[g][o] = acc;
    __syncthreads();
    if (g == 0)
        mean[o] = ((red[0][o] + red[1][o]) + (red[2][o] + red[3][o])) * (1.0f / 1024.0f);
    __syncthreads();

    if (tid < 32) {
        float a = b1[tid];
#pragma unroll
        for (int f = 0; f < 64; ++f) a = fmaf(mean[f], W1[f * 32 + tid], a);
        h1[tid] = fmaxf(a, 0.f);
    }
    __syncthreads();
    if (tid < 16) {
        float a = b2[tid];
#pragma unroll
        for (int f = 0; f < 32; ++f) a = fmaf(h1[f], W2[f * 16 + tid], a);
        h2[tid] = fmaxf(a, 0.f);
    }
    __syncthreads();
    if (tid == 0) {
        float a = b3[0];
#pragma unroll
        for (int f = 0; f < 16; ++f) a = fmaf(h2[f], W3[f], a);
        out[b] = a;
    }
}

// ---------------------------------------------------------------------------
extern "C" void kernel_launch(void* const* d_in, const int* in_sizes, int n_in,
                              void* d_out, int out_size, void* d_ws, size_t ws_size,
                              hipStream_t stream) {
    const float* X   = (const float*)d_in[0];
    const float* A   = (const float*)d_in[1];
    const float* Wq1 = (const float*)d_in[2];
    const float* Wk1 = (const float*)d_in[3];
    const float* Wv1 = (const float*)d_in[4];
    const float* Wo1 = (const float*)d_in[5];
    const float* Wq2 = (const float*)d_in[6];
    const float* Wk2 = (const float*)d_in[7];
    const float* Wv2 = (const float*)d_in[8];
    const float* Wo2 = (const float*)d_in[9];
    const float* W1  = (const float*)d_in[10];
    const float* b1  = (const float*)d_in[11];
    const float* W2  = (const float*)d_in[12];
    const float* b2  = (const float*)d_in[13];
    const float* W3  = (const float*)d_in[14];
    const float* b3  = (const float*)d_in[15];
    float* out = (float*)d_out;

    // workspace layout (u16 units unless noted)
    u32* bits   = (u32*)d_ws;                      // 1 MB
    u16* base   = (u16*)(bits + 262144);
    u16* Qb1    = base;  base += 8388608;
    u16* Kb1    = base;  base += 8388608;
    u16* VT1    = base;  base += 8388608;          // 32-key-group-major V
    u16* ctx1b  = base;  base += 8388608;          // bf16 ctx [B,N,1024]
    u16* WoT1   = base;  base += 131072;           // [128][1024]
    u16* Qb2    = base;  base += 4194304;
    u16* Kb2    = base;  base += 4194304;
    u16* VT2    = base;  base += 4194304;
    u16* ctx2b  = base;  base += 4194304;          // bf16 ctx [B,N,512]
    u16* WoT2   = base;  base += 32768;            // [64][512]
    u16* Xb     = base;  base += 524288;           // bf16 X [8192][64]
    u16* WqkvT1 = base;  base += 196608;           // [3072][64]
    u16* WqkvT2 = base;  base += 196608;           // [1536][128]
    u16* H1b    = base;  base += 1048576;          // bf16 H1 [8192][128]
    float* H2   = (float*)base;                    // f32 [B,N,64] (1MB floats)
    float* partial = H2 + 524288;                  // f32 [8][32][64]

    const int ROWS = NB * NN;                     // 8192
    const float LOG2E = 1.4426950408889634f;

    // prep (independent)
    mask_bits<<<ROWS, 256, 0, stream>>>(A, bits);
    cvt_bf16<<<ROWS * 64 / 8 / 256, 256, 0, stream>>>(X, Xb);
    cvt_qkvT<64, 1024><<<3072 * 64 / 8 / 256, 256, 0, stream>>>(Wq1, Wk1, Wv1, WqkvT1);
    cvt_qkvT<128, 512><<<1536 * 128 / 8 / 256, 256, 0, stream>>>(Wq2, Wk2, Wv2, WqkvT2);
    cvt_woT<1024, 128><<<128 * 1024 / 8 / 256, 256, 0, stream>>>(Wo1, WoT1);
    cvt_woT<512, 64><<<64 * 512 / 8 / 256, 256, 0, stream>>>(Wo2, WoT2);

    // ----- layer 1 (D = 128) -----
    proj_mfma<64, 1024, 128><<<ROWS / 16, 256, 0, stream>>>(
        Xb, WqkvT1, Qb1, Kb1, VT1, 0.08838834764831845f * LOG2E);
    attn_v11<128><<<512, 256, 0, stream>>>(Qb1, Kb1, VT1, bits, ctx1b);
    wo_mfma<1024, 128, true><<<ROWS / 16, 256, 0, stream>>>(ctx1b, WoT1, H1b);

    // ----- layer 2 (D = 64) -----
    proj_mfma<128, 512, 64><<<ROWS / 16, 256, 0, stream>>>(
        H1b, WqkvT2, Qb2, Kb2, VT2, 0.125f * LOG2E);
    attn_v11<64><<<512, 256, 0, stream>>>(Qb2, Kb2, VT2, bits, ctx2b);
    wo_mfma<512, 64, false><<<ROWS / 16, 256, 0, stream>>>(ctx2b, WoT2, H2);

    // ----- pool + MLP (2-stage: parallel reduce, tiny MLP) -----
    pool_partial<<<256, 256, 0, stream>>>(H2, partial);
    pool_mlp2<<<NB, 256, 0, stream>>>(partial, W1, b1, W2, b2, W3, b3, out);
}

// Round 21
// 213.039 us; speedup vs baseline: 1.2626x; 1.0245x over previous
//
#include <hip/hip_runtime.h>
#include <hip/hip_bf16.h>
#include <math.h>

// B=8, N=1024, F=64, HEADS=8, u1=128, u2=64
#define NB 8
#define NN 1024
#define NH 8

typedef __attribute__((ext_vector_type(8))) short bf16x8;
typedef __attribute__((ext_vector_type(4))) float f32x4;
typedef unsigned int u32;
typedef unsigned short u16;

__device__ __forceinline__ u16 f2bf(float f) {
    union { float f; u32 u; } v; v.f = f;
    const u32 u = v.u;
    return (u16)((u + 0x7fffu + ((u >> 16) & 1u)) >> 16);
}

// packed f32x2 -> bf16x2 (RTNE), dst.lo = lo, dst.hi = hi
__device__ __forceinline__ u32 cvt_pk_bf16(float lo, float hi) {
    u32 r;
    asm("v_cvt_pk_bf16_f32 %0, %1, %2" : "=v"(r) : "v"(lo), "v"(hi));
    return r;
}

// ---------------------------------------------------------------------------
// Mask bit-pack: A [B,N,N] f32 (0/1) -> bits [B*N, 32] u32 (bit=1 => masked)
// ---------------------------------------------------------------------------
__global__ __launch_bounds__(256) void mask_bits(const float* __restrict__ A,
                                                 u32* __restrict__ bits) {
    const int row = blockIdx.x;            // 0..B*N-1
    const int tid = threadIdx.x;
    const int lane = tid & 63;
    const float* __restrict__ ar = A + (size_t)row * NN;
#pragma unroll
    for (int it = 0; it < 4; ++it) {
        const int i = it * 256 + tid;
        const unsigned long long bal = __ballot(ar[i] != 0.0f);
        const int w0 = (it * 256 + (tid & ~63)) >> 5;
        if (lane == 0)  bits[(size_t)row * 32 + w0]     = (u32)bal;
        if (lane == 32) bits[(size_t)row * 32 + w0 + 1] = (u32)(bal >> 32);
    }
}

// ---------------------------------------------------------------------------
// f32 -> bf16 vector convert (8 elems/thread).
// ---------------------------------------------------------------------------
__global__ __launch_bounds__(256)
void cvt_bf16(const float* __restrict__ in, u16* __restrict__ out) {
    const int i = blockIdx.x * 256 + threadIdx.x;
    const float4 a = ((const float4*)in)[2 * i];
    const float4 b = ((const float4*)in)[2 * i + 1];
    u16 t[8] = {f2bf(a.x), f2bf(a.y), f2bf(a.z), f2bf(a.w),
                f2bf(b.x), f2bf(b.y), f2bf(b.z), f2bf(b.w)};
    ((uint4*)out)[i] = *(uint4*)t;
}

// ---------------------------------------------------------------------------
// QKV weight transpose+bf16: WT[c][f] over c in [0,3*HD) = {Wq|Wk|Wv}[f][c%HD]
// ---------------------------------------------------------------------------
template <int KIN, int HD>
__global__ __launch_bounds__(256)
void cvt_qkvT(const float* __restrict__ Wq, const float* __restrict__ Wk,
              const float* __restrict__ Wv, u16* __restrict__ WT) {
    const int idx = blockIdx.x * 256 + threadIdx.x;   // c*(KIN/8) + f8
    const int c  = idx / (KIN / 8);
    const int f0 = (idx % (KIN / 8)) * 8;
    const float* __restrict__ W = (c < HD) ? Wq : (c < 2 * HD) ? Wk : Wv;
    const int cc = c % HD;
    u16 tmp[8];
#pragma unroll
    for (int j = 0; j < 8; ++j)
        tmp[j] = f2bf(W[(size_t)(f0 + j) * HD + cc]);
    *(uint4*)&WT[(size_t)c * KIN + f0] = *(uint4*)tmp;
}

// ---------------------------------------------------------------------------
// Wo transpose+bf16: WoT[n][k] = bf16(Wo[k][n]).
// ---------------------------------------------------------------------------
template <int CIN, int COUT>
__global__ __launch_bounds__(256)
void cvt_woT(const float* __restrict__ Wo, u16* __restrict__ WoT) {
    const int idx = blockIdx.x * 256 + threadIdx.x;   // n*CIN/8 + k8
    const int n  = idx / (CIN / 8);
    const int k0 = (idx % (CIN / 8)) * 8;
    u16 tmp[8];
#pragma unroll
    for (int j = 0; j < 8; ++j)
        tmp[j] = f2bf(Wo[(size_t)(k0 + j) * COUT + n]);
    *(uint4*)&WoT[(size_t)n * CIN + k0] = *(uint4*)tmp;
}

// ---------------------------------------------------------------------------
// MFMA QKV projection (R12-verified).  Xb: [rows][KIN] bf16.  WT: [3*HD][KIN].
// Outputs: Qb [bh][n][D] (x qscale), Kb same, VT 32-key-group-major permuted
// [bh][grp32][D][32''] with n'' = 8g + r + 4*grp for this 16-row tile.
// ---------------------------------------------------------------------------
template <int KIN, int HD, int D>
__global__ __launch_bounds__(256)
void proj_mfma(const u16* __restrict__ Xb,
               const u16* __restrict__ WT,
               u16* __restrict__ Qb,
               u16* __restrict__ Kb,
               u16* __restrict__ VT,
               const float qscale) {
    constexpr int NKT = KIN / 32;          // k-steps (2 / 4)
    constexpr int NTW = (3 * HD / 16) / 4; // n-tiles per wave (48 / 24)

    const int tid  = threadIdx.x;
    const int w    = tid >> 6;
    const int lane = tid & 63;
    const int g    = lane >> 4;
    const int q16  = lane & 15;
    const int r0   = blockIdx.x * 16;
    const int b    = r0 >> 10;
    const int n0   = r0 & 1023;
    const int ch   = n0 >> 5;
    const int grp  = (n0 >> 4) & 1;

    bf16x8 af[NKT];
#pragma unroll
    for (int t = 0; t < NKT; ++t)
        af[t] = *(const bf16x8*)&Xb[(size_t)(r0 + q16) * KIN + t * 32 + g * 8];

#pragma unroll 1
    for (int i = 0; i < NTW; ++i) {
        const int nt = w + 4 * i;
        const int c0 = nt * 16;
        f32x4 acc = (f32x4)0.f;
#pragma unroll
        for (int t = 0; t < NKT; ++t) {
            const bf16x8 wf = *(const bf16x8*)&WT[(size_t)(c0 + q16) * KIN + t * 32 + g * 8];
            acc = __builtin_amdgcn_mfma_f32_16x16x32_bf16(af[t], wf, acc, 0, 0, 0);
        }

        const int wcl = c0 / HD;           // 0=Q 1=K 2=V (wave-uniform)
        const int cc  = c0 % HD;
        const int h   = cc / D;
        const int d0  = cc % D;
        const int bh  = b * NH + h;

        if (wcl == 2) {
            u16 tmp[4];
#pragma unroll
            for (int r = 0; r < 4; ++r) tmp[r] = f2bf(acc[r]);
            *(uint2*)&VT[(((size_t)bh * 32 + ch) * D + d0 + q16) * 32
                         + 8 * g + 4 * grp] = *(uint2*)tmp;
        } else {
            u16* __restrict__ O = wcl ? Kb : Qb;
            const float sc = wcl ? 1.0f : qscale;
#pragma unroll
            for (int r = 0; r < 4; ++r)
                O[((size_t)bh * NN + n0 + 4 * g + r) * D + d0 + q16] = f2bf(acc[r] * sc);
        }
    }
}

// ---------------------------------------------------------------------------
// MFMA flash attention v11 (R15/R16-measured best, byte-identical revert):
//   - KVBLK=64 (16 chunks), K LDS swizzled + double-buffered
//   - V LDS stride 144B, (vD,vHalf)->vD*144+vHalf*64 write map
//   - l via ones-MFMA: accL = mfma(pa, ones) -> shuffle-free epilogue
//   - mask-as-select after exp2; s_setprio(1) around MFMA clusters
//   - one barrier per chunk; loads issued 2 chunks ahead
// Grid 512 blocks = 8 XCDs x 8 bh x 8 q-blocks; block = 4 waves x 32q.
// ---------------------------------------------------------------------------
template <int D>
__global__ __launch_bounds__(256, 2)
void attn_v11(const u16* __restrict__ Qb,
              const u16* __restrict__ Kb,
              const u16* __restrict__ VT,
              const u32* __restrict__ bits,
              u16* __restrict__ Ob) {
    constexpr int ND4 = D / 32;            // QK k-steps per 16-key subtile (4/2)
    constexpr int NDT = D / 16;            // PV d-tiles (8/4)
    constexpr int KROWB = 2 * D;           // K LDS row bytes (256/128)
    constexpr int KBYTES = 64 * KROWB;     // 16K / 8K
    constexpr int VROWB = 144;             // 64 keys * 2B + 16B pad
    constexpr int VBYTES = D * VROWB;      // 18K / 9K

    const int tid  = threadIdx.x;
    const int w    = tid >> 6;
    const int lane = tid & 63;
    const int g    = lane >> 4;            // 0..3
    const int q16  = lane & 15;

    // 512 blocks -> 8 XCDs x 8 bh x 8 q-blocks (bijective; bid%8 = XCD)
    const int xcd    = blockIdx.x & 7;
    const int within = blockIdx.x >> 3;    // 0..63
    const int bh     = xcd * 8 + (within >> 3);
    const int b      = bh >> 3, h = bh & 7;
    const int q0     = ((within & 7) * 4 + w) * 32;   // 32 q-rows per wave

    const u16* __restrict__ qbase = Qb + (size_t)bh * NN * D;
    const u16* __restrict__ kbase = Kb + (size_t)bh * NN * D;
    const u16* __restrict__ vbase = VT + (size_t)bh * 32 * D * 32;  // grp32-major
    const u32* __restrict__ brow0 = bits + ((size_t)b * NN + q0 + q16) * 32;
    const u32* __restrict__ brow1 = brow0 + 16 * 32;

    __shared__ alignas(16) char KsB[2][KBYTES];
    __shared__ alignas(16) char VsB[2][VBYTES];

    // staging mapping (64B per thread each for K and V)
    bool doK, doV;
    int kRow = 0, kU0 = 0, vD = 0, vHalf = 0;
    if constexpr (D == 128) {
        doK = true; doV = true;
        kRow = tid >> 2;           kU0 = (tid & 3) * 4;    // 64 rows x 16 units
        vD   = tid >> 1;           vHalf = tid & 1;        // 128 rows x 2 halves
    } else {
        doK = (tid < 128); doV = !doK;
        kRow = (tid & 127) >> 1;   kU0 = (tid & 1) * 4;    // 64 rows x 8 units
        vD   = (tid & 127) >> 1;   vHalf = tid & 1;        // 64 rows x 2 halves
    }

    // Q as B-fragment: col=q16=q, k = f*32 + g*8 + j; 2 q-subtiles
    bf16x8 qf[2][ND4];
#pragma unroll
    for (int qs = 0; qs < 2; ++qs)
#pragma unroll
        for (int f = 0; f < ND4; ++f)
            qf[qs][f] = *(const bf16x8*)
                &qbase[(size_t)(q0 + qs * 16 + q16) * D + f * 32 + g * 8];

    f32x4 acc[2][NDT];
    f32x4 accL[2];
#pragma unroll
    for (int qs = 0; qs < 2; ++qs) {
        accL[qs] = (f32x4)0.f;
#pragma unroll
        for (int dt = 0; dt < NDT; ++dt) acc[qs][dt] = (f32x4)0.f;
    }

    const short oneb = (short)0x3F80;      // bf16 1.0
    const bf16x8 ones = {oneb, oneb, oneb, oneb, oneb, oneb, oneb, oneb};

    uint4 skr0, skr1, skr2, skr3, svr0, svr1, svr2, svr3;
    auto stage_load = [&](int ch) {
        if (doK) {
            const u16* src = kbase + (size_t)(ch * 64 + kRow) * D + kU0 * 8;
            skr0 = *(const uint4*)(src);
            skr1 = *(const uint4*)(src + 8);
            skr2 = *(const uint4*)(src + 16);
            skr3 = *(const uint4*)(src + 24);
        }
        if (doV) {
            const u16* src = vbase + ((size_t)(ch * 2 + vHalf) * D + vD) * 32;
            svr0 = *(const uint4*)(src);
            svr1 = *(const uint4*)(src + 8);
            svr2 = *(const uint4*)(src + 16);
            svr3 = *(const uint4*)(src + 24);
        }
    };
    auto stage_write = [&](int buf) {
        if (doK) {
            char* kr = KsB[buf] + kRow * KROWB;
            *(uint4*)(kr + (((kU0 + 0) ^ (kRow & 7)) * 16)) = skr0;
            *(uint4*)(kr + (((kU0 + 1) ^ (kRow & 7)) * 16)) = skr1;
            *(uint4*)(kr + (((kU0 + 2) ^ (kRow & 7)) * 16)) = skr2;
            *(uint4*)(kr + (((kU0 + 3) ^ (kRow & 7)) * 16)) = skr3;
        }
        if (doV) {
            char* vr = VsB[buf] + vD * VROWB + vHalf * 64;
            *(uint4*)(vr)      = svr0;
            *(uint4*)(vr + 16) = svr1;
            *(uint4*)(vr + 32) = svr2;
            *(uint4*)(vr + 48) = svr3;
        }
    };

    // prologue: buf0 = chunk 0; chunk 1 in regs
    stage_load(0);
    stage_write(0);
    stage_load(1);
    __syncthreads();

#pragma unroll 1
    for (int ch = 0; ch < 16; ++ch) {
        const int cur = ch & 1;
        if (ch + 1 < 16) stage_write(cur ^ 1);
        if (ch + 2 < 16) stage_load(ch + 2);

        const uint2 bwA = *(const uint2*)(brow0 + ch * 2);
        const uint2 bwB = *(const uint2*)(brow1 + ch * 2);

        // QK^T over 4 16-key subtiles (kf loaded per-subtile to cap liveness)
        f32x4 s[2][4];
#pragma unroll
        for (int qs = 0; qs < 2; ++qs)
#pragma unroll
            for (int kb = 0; kb < 4; ++kb) s[qs][kb] = (f32x4)0.f;

        __builtin_amdgcn_s_setprio(1);
#pragma unroll
        for (int kb = 0; kb < 4; ++kb) {
            bf16x8 kf[ND4];
#pragma unroll
            for (int f = 0; f < ND4; ++f)
                kf[f] = *(const bf16x8*)
                    (KsB[cur] + (kb * 16 + q16) * KROWB + (((f * 4 + g) ^ (q16 & 7)) * 16));
#pragma unroll
            for (int f = 0; f < ND4; ++f) {
                s[0][kb] = __builtin_amdgcn_mfma_f32_16x16x32_bf16(kf[f], qf[0][f], s[0][kb], 0, 0, 0);
                s[1][kb] = __builtin_amdgcn_mfma_f32_16x16x32_bf16(kf[f], qf[1][f], s[1][kb], 0, 0, 0);
            }
        }
        __builtin_amdgcn_s_setprio(0);

        // V B-fragments (issue LDS reads before softmax for overlap)
        bf16x8 vf[2][NDT];
#pragma unroll
        for (int kg = 0; kg < 2; ++kg)
#pragma unroll
            for (int dt = 0; dt < NDT; ++dt)
                vf[kg][dt] = *(const bf16x8*)
                    (VsB[cur] + (dt * 16 + q16) * VROWB + kg * 64 + g * 16);

        // softmax (no max tracking): reg r of s[qs][kb] = key kb*16+4g+r
        union { u32 u[4]; bf16x8 v; } pa[2][2];
#pragma unroll
        for (int qs = 0; qs < 2; ++qs) {
            const u32 w0 = qs ? bwB.x : bwA.x;
            const u32 w1 = qs ? bwB.y : bwA.y;
#pragma unroll
            for (int kb = 0; kb < 4; ++kb) {
                const u32 sh = ((kb >> 1) ? w1 : w0) >> (g * 4 + (kb & 1) * 16);
                float p[4];
#pragma unroll
                for (int r = 0; r < 4; ++r) {
                    const float e = exp2f(s[qs][kb][r]);
                    p[r] = ((sh >> r) & 1u) ? 0.f : e;
                }
                pa[qs][kb >> 1].u[(kb & 1) * 2 + 0] = cvt_pk_bf16(p[0], p[1]);
                pa[qs][kb >> 1].u[(kb & 1) * 2 + 1] = cvt_pk_bf16(p[2], p[3]);
            }
        }

        // PV + l-via-ones MFMA
        __builtin_amdgcn_s_setprio(1);
#pragma unroll
        for (int kg = 0; kg < 2; ++kg) {
            accL[0] = __builtin_amdgcn_mfma_f32_16x16x32_bf16(pa[0][kg].v, ones, accL[0], 0, 0, 0);
            accL[1] = __builtin_amdgcn_mfma_f32_16x16x32_bf16(pa[1][kg].v, ones, accL[1], 0, 0, 0);
#pragma unroll
            for (int dt = 0; dt < NDT; ++dt) {
                acc[0][dt] = __builtin_amdgcn_mfma_f32_16x16x32_bf16(pa[0][kg].v, vf[kg][dt], acc[0][dt], 0, 0, 0);
                acc[1][dt] = __builtin_amdgcn_mfma_f32_16x16x32_bf16(pa[1][kg].v, vf[kg][dt], acc[1][dt], 0, 0, 0);
            }
        }
        __builtin_amdgcn_s_setprio(0);

        __syncthreads();
    }

    // epilogue: accL[qs][r] = l for q-row g*4+r (C-layout) -> no shuffles
#pragma unroll
    for (int qs = 0; qs < 2; ++qs) {
        float ivr[4];
#pragma unroll
        for (int r = 0; r < 4; ++r) ivr[r] = 1.0f / accL[qs][r];
#pragma unroll
        for (int dt = 0; dt < NDT; ++dt)
#pragma unroll
            for (int r = 0; r < 4; ++r) {
                const int q = q0 + qs * 16 + g * 4 + r;
                Ob[(((size_t)b * NN + q) * NH + h) * D + dt * 16 + q16] =
                    f2bf(acc[qs][dt][r] * ivr[r]);
            }
    }
}

// ---------------------------------------------------------------------------
// Output projection via MFMA (R11/R12-verified).
// ---------------------------------------------------------------------------
template <int CIN, int COUT, bool BF16OUT>
__global__ __launch_bounds__(256)
void wo_mfma(const u16* __restrict__ ctxb,
             const u16* __restrict__ WoT,
             void* __restrict__ Hout) {
    constexpr int NTW = COUT / 64;         // n-tiles per wave (2 / 1)
    const int tid  = threadIdx.x;
    const int w    = tid >> 6;
    const int lane = tid & 63;
    const int g    = lane >> 4;
    const int q16  = lane & 15;
    const int r0   = blockIdx.x * 16;

    f32x4 acc[NTW];
#pragma unroll
    for (int nt = 0; nt < NTW; ++nt) acc[nt] = (f32x4)0.f;

    const u16* __restrict__ arow = ctxb + (size_t)(r0 + q16) * CIN + g * 8;

#pragma unroll 4
    for (int k0 = 0; k0 < CIN; k0 += 32) {
        const bf16x8 af = *(const bf16x8*)(arow + k0);
#pragma unroll
        for (int nt = 0; nt < NTW; ++nt) {
            const int n = (w * NTW + nt) * 16 + q16;
            const bf16x8 wf = *(const bf16x8*)&WoT[(size_t)n * CIN + k0 + g * 8];
            acc[nt] = __builtin_amdgcn_mfma_f32_16x16x32_bf16(af, wf, acc[nt], 0, 0, 0);
        }
    }

#pragma unroll
    for (int nt = 0; nt < NTW; ++nt)
#pragma unroll
        for (int r = 0; r < 4; ++r) {
            const size_t off = (size_t)(r0 + 4 * g + r) * COUT + (w * NTW + nt) * 16 + q16;
            if constexpr (BF16OUT) ((u16*)Hout)[off] = f2bf(acc[nt][r]);
            else                   ((float*)Hout)[off] = acc[nt][r];
        }
}

// ---------------------------------------------------------------------------
// Pool stage 1: partial sums.  Grid 256 blocks = 8 b x 32 chunks of 32 rows.
// ---------------------------------------------------------------------------
__global__ __launch_bounds__(256)
void pool_partial(const float* __restrict__ H2, float* __restrict__ partial) {
    const int b  = blockIdx.x >> 5;
    const int ch = blockIdx.x & 31;
    const int tid = threadIdx.x;
    const int o = tid & 63;
    const int g = tid >> 6;

    __shared__ float red[4][64];
    float acc = 0.f;
#pragma unroll
    for (int i = 0; i < 8; ++i) {
        const int n = ch * 32 + g * 8 + i;
        acc += H2[((size_t)b * NN + n) * 64 + o];
    }
    red[g][o] = acc;
    __syncthreads();
    if (g == 0)
        partial[((size_t)b * 32 + ch) * 64 + o] =
            (red[0][o] + red[1][o]) + (red[2][o] + red[3][o]);
}

// ---------------------------------------------------------------------------
// Pool stage 2: final reduce + 3-layer MLP.  8 blocks (one per b).
// ---------------------------------------------------------------------------
__global__ __launch_bounds__(256)
void pool_mlp2(const float* __restrict__ partial,
               const float* __restrict__ W1, const float* __restrict__ b1,
               const float* __restrict__ W2, const float* __restrict__ b2,
               const float* __restrict__ W3, const float* __restrict__ b3,
               float* __restrict__ out) {
    const int b = blockIdx.x;
    const int tid = threadIdx.x;       // 256
    const int o = tid & 63;
    const int g = tid >> 6;
    __shared__ float red[4][64];
    __shared__ float mean[64];
    __shared__ float h1[32];
    __shared__ float h2[16];

    float acc = 0.f;
#pragma unroll
    for (int c = 0; c < 8; ++c)
        acc += partial[((size_t)b * 32 + g * 8 + c) * 64 + o];
    red[g][o] = acc;
    __syncthreads();
    if (g == 0)
        mean[o] = ((red[0][o] + red[1][o]) + (red[2][o] + red[3][o])) * (1.0f / 1024.0f);
    __syncthreads();

    if (tid < 32) {
        float a = b1[tid];
#pragma unroll
        for (int f = 0; f < 64; ++f) a = fmaf(mean[f], W1[f * 32 + tid], a);
        h1[tid] = fmaxf(a, 0.f);
    }
    __syncthreads();
    if (tid < 16) {
        float a = b2[tid];
#pragma unroll
        for (int f = 0; f < 32; ++f) a = fmaf(h1[f], W2[f * 16 + tid], a);
        h2[tid] = fmaxf(a, 0.f);
    }
    __syncthreads();
    if (tid == 0) {
        float a = b3[0];
#pragma unroll
        for (int f = 0; f < 16; ++f) a = fmaf(h2[f], W3[f], a);
        out[b] = a;
    }
}

// ---------------------------------------------------------------------------
extern "C" void kernel_launch(void* const* d_in, const int* in_sizes, int n_in,
                              void* d_out, int out_size, void* d_ws, size_t ws_size,
                              hipStream_t stream) {
    const float* X   = (const float*)d_in[0];
    const float* A   = (const float*)d_in[1];
    const float* Wq1 = (const float*)d_in[2];
    const float* Wk1 = (const float*)d_in[3];
    const float* Wv1 = (const float*)d_in[4];
    const float* Wo1 = (const float*)d_in[5];
    const float* Wq2 = (const float*)d_in[6];
    const float* Wk2 = (const float*)d_in[7];
    const float* Wv2 = (const float*)d_in[8];
    const float* Wo2 = (const float*)d_in[9];
    const float* W1  = (const float*)d_in[10];
    const float* b1  = (const float*)d_in[11];
    const float* W2  = (const float*)d_in[12];
    const float* b2  = (const float*)d_in[13];
    const float* W3  = (const float*)d_in[14];
    const float* b3  = (const float*)d_in[15];
    float* out = (float*)d_out;

    // workspace layout (u16 units unless noted)
    u32* bits   = (u32*)d_ws;                      // 1 MB
    u16* base   = (u16*)(bits + 262144);
    u16* Qb1    = base;  base += 8388608;
    u16* Kb1    = base;  base += 8388608;
    u16* VT1    = base;  base += 8388608;          // 32-key-group-major V
    u16* ctx1b  = base;  base += 8388608;          // bf16 ctx [B,N,1024]
    u16* WoT1   = base;  base += 131072;           // [128][1024]
    u16* Qb2    = base;  base += 4194304;
    u16* Kb2    = base;  base += 4194304;
    u16* VT2    = base;  base += 4194304;
    u16* ctx2b  = base;  base += 4194304;          // bf16 ctx [B,N,512]
    u16* WoT2   = base;  base += 32768;            // [64][512]
    u16* Xb     = base;  base += 524288;           // bf16 X [8192][64]
    u16* WqkvT1 = base;  base += 196608;           // [3072][64]
    u16* WqkvT2 = base;  base += 196608;           // [1536][128]
    u16* H1b    = base;  base += 1048576;          // bf16 H1 [8192][128]
    float* H2   = (float*)base;                    // f32 [B,N,64] (1MB floats)
    float* partial = H2 + 524288;                  // f32 [8][32][64]

    const int ROWS = NB * NN;                     // 8192
    const float LOG2E = 1.4426950408889634f;

    // prep (independent)
    mask_bits<<<ROWS, 256, 0, stream>>>(A, bits);
    cvt_bf16<<<ROWS * 64 / 8 / 256, 256, 0, stream>>>(X, Xb);
    cvt_qkvT<64, 1024><<<3072 * 64 / 8 / 256, 256, 0, stream>>>(Wq1, Wk1, Wv1, WqkvT1);
    cvt_qkvT<128, 512><<<1536 * 128 / 8 / 256, 256, 0, stream>>>(Wq2, Wk2, Wv2, WqkvT2);
    cvt_woT<1024, 128><<<128 * 1024 / 8 / 256, 256, 0, stream>>>(Wo1, WoT1);
    cvt_woT<512, 64><<<64 * 512 / 8 / 256, 256, 0, stream>>>(Wo2, WoT2);

    // ----- layer 1 (D = 128) -----
    proj_mfma<64, 1024, 128><<<ROWS / 16, 256, 0, stream>>>(
        Xb, WqkvT1, Qb1, Kb1, VT1, 0.08838834764831845f * LOG2E);
    attn_v11<128><<<512, 256, 0, stream>>>(Qb1, Kb1, VT1, bits, ctx1b);
    wo_mfma<1024, 128, true><<<ROWS / 16, 256, 0, stream>>>(ctx1b, WoT1, H1b);

    // ----- layer 2 (D = 64) -----
    proj_mfma<128, 512, 64><<<ROWS / 16, 256, 0, stream>>>(
        H1b, WqkvT2, Qb2, Kb2, VT2, 0.125f * LOG2E);
    attn_v11<64><<<512, 256, 0, stream>>>(Qb2, Kb2, VT2, bits, ctx2b);
    wo_mfma<512, 64, false><<<ROWS / 16, 256, 0, stream>>>(ctx2b, WoT2, H2);

    // ----- pool + MLP (2-stage: parallel reduce, tiny MLP) -----
    pool_partial<<<256, 256, 0, stream>>>(H2, partial);
    pool_mlp2<<<NB, 256, 0, stream>>>(partial, W1, b1, W2, b2, W3, b3, out);
}